// Round 1
// baseline (418.978 us; speedup 1.0000x reference)
//
#include <hip/hip_runtime.h>
#include <hip/hip_bf16.h>

// Conv2d 3x3 s1 p1, NCHW fp32: implicit GEMM on MFMA bf16 with fp32 hi/lo split.
// M = out-channels (256), N = pixels (100352), K = C*9 = 1152.
// 3-MFMA split: x*w ~= xhi*whi + xlo*whi + xhi*wlo  (residual ~2^-17 rel).

typedef __attribute__((ext_vector_type(8))) short short8;
typedef __attribute__((ext_vector_type(4))) float floatx4;

#define NN   32
#define CC   128
#define HH   56
#define WW   56
#define KOUT 256
#define HWs  3136            // 56*56
#define CHW  (CC * HWs)
#define WT_ELEMS (9 * KOUT * CC)   // 294912 per array (hi / lo)

__device__ __forceinline__ void f32_to_bf16pair(float x, short& hi, short& lo) {
    __hip_bfloat16 h = __float2bfloat16(x);          // RNE
    float hf = __bfloat162float(h);
    __hip_bfloat16 l = __float2bfloat16(x - hf);
    hi = __builtin_bit_cast(short, h);
    lo = __builtin_bit_cast(short, l);
}

// ---- prep: W[k][c][r][s] fp32 -> Wt_hi/Wt_lo[rs][k][c] bf16 ----------------
__global__ __launch_bounds__(256) void prep_w(const float* __restrict__ Wsrc,
                                              short* __restrict__ whi,
                                              short* __restrict__ wlo) {
    int e  = blockIdx.x * 256 + threadIdx.x;   // 0..294911
    int rs = e >> 15;                          // /(256*128)
    int kc = e & 32767;
    int k  = kc >> 7;
    int c  = kc & 127;
    float wv = Wsrc[(k * CC + c) * 9 + rs];
    short hi, lo;
    f32_to_bf16pair(wv, hi, lo);
    whi[e] = hi;
    wlo[e] = lo;
}

// ---- main: 128(chan) x 128(pix) tile, BK=64 over C, rs outer ---------------
__global__ __launch_bounds__(256, 2) void conv_mfma(
    const float* __restrict__ X, const short* __restrict__ whi,
    const short* __restrict__ wlo, const float* __restrict__ bias,
    float* __restrict__ out) {

    __shared__ __align__(16) short smem[32768];        // 64 KB: Ahi|Alo|Bhi|Blo
    const int A_HI = 0, A_LO = 8192, B_HI = 16384, B_LO = 24576;

    const int tid  = threadIdx.x;
    const int lane = tid & 63;
    const int wid  = tid >> 6;
    const int wr   = wid >> 1;       // channel 64-half
    const int wc   = wid & 1;        // pixel 64-half
    const int pblk = blockIdx.x;     // 0..783  (pixel blocks)
    const int kblk = blockIdx.y;     // 0..1    (channel blocks)

    // B-staging (X/im2col) per-thread constants
    const int prow = tid & 127;
    const unsigned p = pblk * 128 + prow;
    const int n  = p / HWs;
    const int hw = p % HWs;
    const int h  = hw / WW;
    const int w  = hw % WW;
    const int oct = tid >> 7;        // 0/1: which 8-c octet

    // A-staging (weights) per-thread constants
    const int akrow  = tid >> 1;             // 0..127
    const int achalf = (tid & 1) * 32;

    floatx4 acc[4][4];
#pragma unroll
    for (int i = 0; i < 4; i++)
#pragma unroll
        for (int j = 0; j < 4; j++) acc[i][j] = (floatx4)(0.0f);

    for (int kstep = 0; kstep < 18; ++kstep) {
        const int rs = kstep >> 1;           // tap index 0..8
        const int ct = kstep & 1;
        const int c0 = ct * 64;

        if (kstep) __syncthreads();          // LDS readers of prev step done

        // ---- stage A: weights [128 k][64 c], hi+lo (bf16 global loads)
        {
            const int gbase = (rs * KOUT + kblk * 128 + akrow) * CC + c0 + achalf;
#pragma unroll
            for (int j = 0; j < 4; ++j) {
                short8 vh = *(const short8*)(whi + gbase + j * 8);
                short8 vl = *(const short8*)(wlo + gbase + j * 8);
                const int ci  = achalf + j * 8;
                const int idx = (akrow << 6) + (((ci >> 3) ^ (akrow & 7)) << 3);
                *(short8*)&smem[A_HI + idx] = vh;
                *(short8*)&smem[A_LO + idx] = vl;
            }
        }
        // ---- stage B: X tile [128 pix][64 c], im2col + zero-fill, cvt hi/lo
        {
            const int dh = rs / 3 - 1, dw = rs % 3 - 1;
            const int ih = h + dh, iw = w + dw;
            const bool valid = ((unsigned)ih < 56u) && ((unsigned)iw < 56u);
            const int bofs = n * CHW + ih * WW + iw;   // only used when valid
#pragma unroll
            for (int pass = 0; pass < 4; ++pass) {
                const int cbase = pass * 16 + oct * 8;
                short hi8[8], lo8[8];
#pragma unroll
                for (int j = 0; j < 8; ++j) {
                    float xv = 0.0f;
                    if (valid) xv = X[bofs + (c0 + cbase + j) * HWs];
                    f32_to_bf16pair(xv, hi8[j], lo8[j]);
                }
                const int idx = (prow << 6) + (((cbase >> 3) ^ (prow & 7)) << 3);
                *(short8*)&smem[B_HI + idx] = *(short8*)hi8;
                *(short8*)&smem[B_LO + idx] = *(short8*)lo8;
            }
        }
        __syncthreads();

        // ---- compute: 2 k-substeps x (16 frag reads + 48 MFMA)
#pragma unroll
        for (int ksub = 0; ksub < 2; ++ksub) {
            const int kc8 = ksub * 32 + ((lane >> 4) << 3);
            short8 ah[4], al[4], bh[4], bl[4];
#pragma unroll
            for (int t = 0; t < 4; ++t) {
                const int ar = wr * 64 + t * 16 + (lane & 15);
                const int ai = (ar << 6) + (((kc8 >> 3) ^ (ar & 7)) << 3);
                ah[t] = *(const short8*)&smem[A_HI + ai];
                al[t] = *(const short8*)&smem[A_LO + ai];
                const int br = wc * 64 + t * 16 + (lane & 15);
                const int bi = (br << 6) + (((kc8 >> 3) ^ (br & 7)) << 3);
                bh[t] = *(const short8*)&smem[B_HI + bi];
                bl[t] = *(const short8*)&smem[B_LO + bi];
            }
#pragma unroll
            for (int mt = 0; mt < 4; ++mt)
#pragma unroll
                for (int nt = 0; nt < 4; ++nt) {
                    acc[mt][nt] = __builtin_amdgcn_mfma_f32_16x16x32_bf16(
                        ah[mt], bh[nt], acc[mt][nt], 0, 0, 0);
                    acc[mt][nt] = __builtin_amdgcn_mfma_f32_16x16x32_bf16(
                        al[mt], bh[nt], acc[mt][nt], 0, 0, 0);
                    acc[mt][nt] = __builtin_amdgcn_mfma_f32_16x16x32_bf16(
                        ah[mt], bl[nt], acc[mt][nt], 0, 0, 0);
                }
        }
    }

    // ---- epilogue: C/D frag (col=lane&15 -> pixel, row=(lane>>4)*4+r -> chan)
#pragma unroll
    for (int mt = 0; mt < 4; ++mt) {
        const int kch0 = kblk * 128 + wr * 64 + mt * 16 + ((lane >> 4) << 2);
#pragma unroll
        for (int nt = 0; nt < 4; ++nt) {
            const unsigned pp  = pblk * 128 + wc * 64 + nt * 16 + (lane & 15);
            const unsigned nn  = pp / HWs;     // 16-pixel tiles never straddle n
            const unsigned hw2 = pp % HWs;
            float* ob = out + ((long)nn * KOUT + kch0) * HWs + hw2;
#pragma unroll
            for (int r = 0; r < 4; ++r) {
                ob[(long)r * HWs] = acc[mt][nt][r] + bias[kch0 + r];
            }
        }
    }
}

// ---- fallback (only if ws too small): correct naive direct conv ------------
__global__ __launch_bounds__(256) void conv_naive(const float* __restrict__ X,
                                                  const float* __restrict__ Wt,
                                                  const float* __restrict__ bias,
                                                  float* __restrict__ out) {
    long o = (long)blockIdx.x * 256 + threadIdx.x;   // < 25690112
    int w_ = o % WW;
    long t1 = o / WW;
    int h_ = t1 % HH;
    long t2 = t1 / HH;
    int k_ = t2 % KOUT;
    int n_ = (int)(t2 / KOUT);
    float acc = bias[k_];
    for (int c = 0; c < CC; ++c)
        for (int r = 0; r < 3; ++r) {
            int ih = h_ + r - 1;
            if ((unsigned)ih >= 56u) continue;
            for (int s = 0; s < 3; ++s) {
                int iw = w_ + s - 1;
                if ((unsigned)iw >= 56u) continue;
                acc += X[((long)(n_ * CC + c) * HH + ih) * WW + iw] *
                       Wt[((k_ * CC + c) * 3 + r) * 3 + s];
            }
        }
    out[o] = acc;
}

extern "C" void kernel_launch(void* const* d_in, const int* in_sizes, int n_in,
                              void* d_out, int out_size, void* d_ws, size_t ws_size,
                              hipStream_t stream) {
    const float* X    = (const float*)d_in[0];
    const float* Wt   = (const float*)d_in[1];
    const float* bias = (const float*)d_in[2];
    float* out        = (float*)d_out;

    if (ws_size >= (size_t)(2 * WT_ELEMS * sizeof(short))) {
        short* whi = (short*)d_ws;
        short* wlo = whi + WT_ELEMS;
        prep_w<<<WT_ELEMS / 256, 256, 0, stream>>>(Wt, whi, wlo);
        conv_mfma<<<dim3(784, 2), 256, 0, stream>>>(X, whi, wlo, bias, out);
    } else {
        conv_naive<<<100352, 256, 0, stream>>>(X, Wt, bias, out);
    }
}

// Round 4
// 228.760 us; speedup vs baseline: 1.8315x; 1.8315x over previous
//
#include <hip/hip_runtime.h>
#include <hip/hip_bf16.h>

// Conv2d 3x3 s1 p1, NCHW fp32 -> implicit GEMM, single f16 MFMA per product.
// M = out-channels (256, full per block), N = pixels (100352), K = C*9 = 1152.
// Pre-pass: X -> zero-padded NHWC f16 (no halo predication, c-contiguous),
//           W -> LDS-image-ordered f16 tiles with XOR bank swizzle baked in.
// Main loop stages exclusively via global_load_lds width=16.

typedef __attribute__((ext_vector_type(8))) short short8;
typedef __attribute__((ext_vector_type(8))) _Float16 half8;
typedef __attribute__((ext_vector_type(4))) float floatx4;

#define NN    32
#define CC    128
#define HH    56
#define WW    56
#define KOUT  256
#define HWs   3136                    // 56*56
#define HP    58                      // padded H/W
#define HPP   (HP * HP)               // 3364
#define XP_SHORTS ((size_t)NN * HPP * CC)        // 13,778,944 f16
#define WT_TILE_SHORTS 16384                     // 256k x 64c per kstep
#define WT_SHORTS (18 * WT_TILE_SHORTS)          // 294,912
#define WS_NEED_NEW ((XP_SHORTS + WT_SHORTS) * sizeof(short))
#define WT_ELEMS (9 * KOUT * CC)      // old-path arrays

__device__ __forceinline__ void gload_lds16(const void* g, void* l) {
    __builtin_amdgcn_global_load_lds(
        (const __attribute__((address_space(1))) unsigned int*)g,
        (__attribute__((address_space(3))) unsigned int*)l, 16, 0, 0);
}

// ---- prep: X[n][c][h][w] fp32 -> Xp[n][h+1][w+1][c] f16 (borders pre-zeroed)
__global__ __launch_bounds__(256) void prep_x(const float* __restrict__ X,
                                              short* __restrict__ Xp) {
    const int nh = blockIdx.x;            // 0..1791 = n*56 + h
    const int n  = nh / HH;
    const int h  = nh % HH;
    const int coct = threadIdx.x & 15;    // c octet 0..15
    const int wq   = threadIdx.x >> 4;    // 0..15 -> w strided
#pragma unroll
    for (int it = 0; it < 4; ++it) {
        const int w = it * 16 + wq;
        if (w < WW) {
            _Float16 v[8];
#pragma unroll
            for (int j = 0; j < 8; ++j)
                v[j] = (_Float16)X[((size_t)(n * CC + coct * 8 + j)) * HWs + h * WW + w];
            *(half8*)&Xp[((size_t)n * HPP + (h + 1) * HP + (w + 1)) * CC + coct * 8] =
                *(half8*)v;
        }
    }
}

// ---- prep: W[k][c][3][3] fp32 -> 18 LDS-image tiles (swizzle baked) --------
__global__ __launch_bounds__(256) void prep_w2(const float* __restrict__ Wsrc,
                                               short* __restrict__ Wt) {
    const int gid  = blockIdx.x * 256 + threadIdx.x;  // 0..36863 (16B units)
    const int tile = gid >> 11;                       // kstep 0..17
    const int u    = gid & 2047;
    const int row  = u >> 3;                          // out-channel 0..255
    const int opys = u & 7;                           // phys octet
    const int rs   = tile >> 1;
    const int ct   = tile & 1;
    const int c0   = ct * 64 + ((opys ^ (row & 7)) << 3);  // logical c
    _Float16 v[8];
#pragma unroll
    for (int j = 0; j < 8; ++j)
        v[j] = (_Float16)Wsrc[((size_t)row * CC + c0 + j) * 9 + rs];
    *(half8*)&Wt[(size_t)tile * WT_TILE_SHORTS + u * 8] = *(half8*)v;
}

// ---- main: 256(ch) x 128(pix) tile, 4 waves (wave tile 128x64), BK=64 ------
__global__ __launch_bounds__(256, 2) void conv_mfma2(
    const short* __restrict__ Xp, const short* __restrict__ Wt,
    const float* __restrict__ bias, float* __restrict__ out) {

    __shared__ __align__(16) short smem[24576];   // 48 KB: A 32KB | B 16KB
    short* const smemA = smem;
    short* const smemB = smem + 16384;

    const int tid  = threadIdx.x;
    const int lane = tid & 63;
    const int wid  = tid >> 6;
    const int wr   = wid >> 1;               // ch 128-half
    const int wc   = wid & 1;                // pix 64-half
    const int bid  = blockIdx.x;             // 0..783
    const int pblk = (bid & 7) * 98 + (bid >> 3);   // XCD-bijective swizzle

    // B-stage per-lane bases: 4 chunks, row = (wid*4+i)*8 + (lane>>3)
    const int swzoct = (lane & 7) ^ (lane >> 3);    // logical octet (row&7 = lane>>3)
    const short* vsrc[4];
#pragma unroll
    for (int i = 0; i < 4; ++i) {
        const int row = (wid * 4 + i) * 8 + (lane >> 3);
        const int p   = pblk * 128 + row;
        const int n   = p / HWs;
        const int hw  = p % HWs;
        const int h   = hw / WW;
        const int w   = hw % WW;
        vsrc[i] = Xp + ((size_t)n * HPP + (h + 1) * HP + (w + 1)) * CC + swzoct * 8;
    }

    floatx4 acc[8][4];
#pragma unroll
    for (int i = 0; i < 8; ++i)
#pragma unroll
        for (int j = 0; j < 4; ++j) acc[i][j] = (floatx4)(0.0f);

    for (int kstep = 0; kstep < 18; ++kstep) {
        const int rs = kstep >> 1;
        const int ct = kstep & 1;
        const int dh = rs / 3 - 1, dw = rs % 3 - 1;
        const int tapoff = (dh * HP + dw) * CC + ct * 64;   // shorts

        if (kstep) __syncthreads();

        // stage A: 32KB, 8 chunks/wave, linear (swizzle baked in Wt)
        {
            const short* asrc = Wt + (size_t)kstep * WT_TILE_SHORTS + wid * 4096 + lane * 8;
#pragma unroll
            for (int i = 0; i < 8; ++i)
                gload_lds16(asrc + i * 512, &smemA[(wid * 8 + i) * 512]);
        }
        // stage B: 16KB, 4 chunks/wave, per-lane pre-swizzled source
#pragma unroll
        for (int i = 0; i < 4; ++i)
            gload_lds16(vsrc[i] + tapoff, &smemB[(wid * 4 + i) * 512]);

        __syncthreads();

        // compute: 2 k-substeps x (12 ds_read_b128 + 32 MFMA)
#pragma unroll
        for (int ksub = 0; ksub < 2; ++ksub) {
            const int koct = ksub * 4 + (lane >> 4);
            half8 ah[8], bh[4];
#pragma unroll
            for (int mt = 0; mt < 8; ++mt) {
                const int ar = wr * 128 + mt * 16 + (lane & 15);
                ah[mt] = *(const half8*)&smemA[ar * 64 + ((koct ^ (ar & 7)) << 3)];
            }
#pragma unroll
            for (int nt = 0; nt < 4; ++nt) {
                const int br = wc * 64 + nt * 16 + (lane & 15);
                bh[nt] = *(const half8*)&smemB[br * 64 + ((koct ^ (br & 7)) << 3)];
            }
#pragma unroll
            for (int mt = 0; mt < 8; ++mt)
#pragma unroll
                for (int nt = 0; nt < 4; ++nt)
                    acc[mt][nt] = __builtin_amdgcn_mfma_f32_16x16x32_f16(
                        ah[mt], bh[nt], acc[mt][nt], 0, 0, 0);
        }
    }

    // epilogue: C/D col=lane&15 -> pixel, row=(lane>>4)*4+r -> channel
#pragma unroll
    for (int mt = 0; mt < 8; ++mt) {
        const int ch = wr * 128 + mt * 16 + ((lane >> 4) << 2);
#pragma unroll
        for (int nt = 0; nt < 4; ++nt) {
            const int p  = pblk * 128 + wc * 64 + nt * 16 + (lane & 15);
            const int n  = p / HWs;          // 16-pix groups never straddle n
            const int hw = p % HWs;
            float* ob = out + ((size_t)n * KOUT + ch) * HWs + hw;
#pragma unroll
            for (int r = 0; r < 4; ++r)
                ob[(size_t)r * HWs] = acc[mt][nt][r] + bias[ch + r];
        }
    }
}

// ======================= fallback tier 2 (proven, 342us) ====================
__device__ __forceinline__ void f32_to_bf16pair(float x, short& hi, short& lo) {
    __hip_bfloat16 h = __float2bfloat16(x);
    float hf = __bfloat162float(h);
    __hip_bfloat16 l = __float2bfloat16(x - hf);
    hi = __builtin_bit_cast(short, h);
    lo = __builtin_bit_cast(short, l);
}

__global__ __launch_bounds__(256) void prep_w(const float* __restrict__ Wsrc,
                                              short* __restrict__ whi,
                                              short* __restrict__ wlo) {
    int e  = blockIdx.x * 256 + threadIdx.x;
    int rs = e >> 15;
    int kc = e & 32767;
    int k  = kc >> 7;
    int c  = kc & 127;
    float wv = Wsrc[(k * CC + c) * 9 + rs];
    short hi, lo;
    f32_to_bf16pair(wv, hi, lo);
    whi[e] = hi;
    wlo[e] = lo;
}

__global__ __launch_bounds__(256, 2) void conv_mfma(
    const float* __restrict__ X, const short* __restrict__ whi,
    const short* __restrict__ wlo, const float* __restrict__ bias,
    float* __restrict__ out) {

    __shared__ __align__(16) short smem[32768];
    const int A_HI = 0, A_LO = 8192, B_HI = 16384, B_LO = 24576;
    const int tid  = threadIdx.x;
    const int lane = tid & 63;
    const int wid  = tid >> 6;
    const int wr   = wid >> 1;
    const int wc   = wid & 1;
    const int pblk = blockIdx.x;
    const int kblk = blockIdx.y;

    const int prow = tid & 127;
    const unsigned p = pblk * 128 + prow;
    const int n  = p / HWs;
    const int hw = p % HWs;
    const int h  = hw / WW;
    const int w  = hw % WW;
    const int oct = tid >> 7;
    const int akrow  = tid >> 1;
    const int achalf = (tid & 1) * 32;

    floatx4 acc[4][4];
#pragma unroll
    for (int i = 0; i < 4; i++)
#pragma unroll
        for (int j = 0; j < 4; j++) acc[i][j] = (floatx4)(0.0f);

    for (int kstep = 0; kstep < 18; ++kstep) {
        const int rs = kstep >> 1;
        const int ct = kstep & 1;
        const int c0 = ct * 64;
        if (kstep) __syncthreads();
        {
            const int gbase = (rs * KOUT + kblk * 128 + akrow) * CC + c0 + achalf;
#pragma unroll
            for (int j = 0; j < 4; ++j) {
                short8 vh = *(const short8*)(whi + gbase + j * 8);
                short8 vl = *(const short8*)(wlo + gbase + j * 8);
                const int ci  = achalf + j * 8;
                const int idx = (akrow << 6) + (((ci >> 3) ^ (akrow & 7)) << 3);
                *(short8*)&smem[A_HI + idx] = vh;
                *(short8*)&smem[A_LO + idx] = vl;
            }
        }
        {
            const int dh = rs / 3 - 1, dw = rs % 3 - 1;
            const int ih = h + dh, iw = w + dw;
            const bool valid = ((unsigned)ih < 56u) && ((unsigned)iw < 56u);
            const int bofs = n * (CC * HWs) + ih * WW + iw;
#pragma unroll
            for (int pass = 0; pass < 4; ++pass) {
                const int cbase = pass * 16 + oct * 8;
                short hi8[8], lo8[8];
#pragma unroll
                for (int j = 0; j < 8; ++j) {
                    float xv = 0.0f;
                    if (valid) xv = X[bofs + (c0 + cbase + j) * HWs];
                    f32_to_bf16pair(xv, hi8[j], lo8[j]);
                }
                const int idx = (prow << 6) + (((cbase >> 3) ^ (prow & 7)) << 3);
                *(short8*)&smem[B_HI + idx] = *(short8*)hi8;
                *(short8*)&smem[B_LO + idx] = *(short8*)lo8;
            }
        }
        __syncthreads();
#pragma unroll
        for (int ksub = 0; ksub < 2; ++ksub) {
            const int kc8 = ksub * 32 + ((lane >> 4) << 3);
            short8 ah[4], al[4], bh[4], bl[4];
#pragma unroll
            for (int t = 0; t < 4; ++t) {
                const int ar = wr * 64 + t * 16 + (lane & 15);
                const int ai = (ar << 6) + (((kc8 >> 3) ^ (ar & 7)) << 3);
                ah[t] = *(const short8*)&smem[A_HI + ai];
                al[t] = *(const short8*)&smem[A_LO + ai];
                const int br = wc * 64 + t * 16 + (lane & 15);
                const int bi = (br << 6) + (((kc8 >> 3) ^ (br & 7)) << 3);
                bh[t] = *(const short8*)&smem[B_HI + bi];
                bl[t] = *(const short8*)&smem[B_LO + bi];
            }
#pragma unroll
            for (int mt = 0; mt < 4; ++mt)
#pragma unroll
                for (int nt = 0; nt < 4; ++nt) {
                    acc[mt][nt] = __builtin_amdgcn_mfma_f32_16x16x32_bf16(
                        ah[mt], bh[nt], acc[mt][nt], 0, 0, 0);
                    acc[mt][nt] = __builtin_amdgcn_mfma_f32_16x16x32_bf16(
                        al[mt], bh[nt], acc[mt][nt], 0, 0, 0);
                    acc[mt][nt] = __builtin_amdgcn_mfma_f32_16x16x32_bf16(
                        ah[mt], bl[nt], acc[mt][nt], 0, 0, 0);
                }
        }
    }
#pragma unroll
    for (int mt = 0; mt < 4; ++mt) {
        const int kch0 = kblk * 128 + wr * 64 + mt * 16 + ((lane >> 4) << 2);
#pragma unroll
        for (int nt = 0; nt < 4; ++nt) {
            const unsigned pp  = pblk * 128 + wc * 64 + nt * 16 + (lane & 15);
            const unsigned nn  = pp / HWs;
            const unsigned hw2 = pp % HWs;
            float* ob = out + ((long)nn * KOUT + kch0) * HWs + hw2;
#pragma unroll
            for (int r = 0; r < 4; ++r)
                ob[(long)r * HWs] = acc[mt][nt][r] + bias[kch0 + r];
        }
    }
}

// ---- tier 3: naive ---------------------------------------------------------
__global__ __launch_bounds__(256) void conv_naive(const float* __restrict__ X,
                                                  const float* __restrict__ Wt,
                                                  const float* __restrict__ bias,
                                                  float* __restrict__ out) {
    long o = (long)blockIdx.x * 256 + threadIdx.x;
    int w_ = o % WW;
    long t1 = o / WW;
    int h_ = t1 % HH;
    long t2 = t1 / HH;
    int k_ = t2 % KOUT;
    int n_ = (int)(t2 / KOUT);
    float acc = bias[k_];
    for (int c = 0; c < CC; ++c)
        for (int r = 0; r < 3; ++r) {
            int ih = h_ + r - 1;
            if ((unsigned)ih >= 56u) continue;
            for (int s = 0; s < 3; ++s) {
                int iw = w_ + s - 1;
                if ((unsigned)iw >= 56u) continue;
                acc += X[((long)(n_ * CC + c) * HH + ih) * WW + iw] *
                       Wt[((k_ * CC + c) * 3 + r) * 3 + s];
            }
        }
    out[o] = acc;
}

extern "C" void kernel_launch(void* const* d_in, const int* in_sizes, int n_in,
                              void* d_out, int out_size, void* d_ws, size_t ws_size,
                              hipStream_t stream) {
    const float* X    = (const float*)d_in[0];
    const float* Wsrc = (const float*)d_in[1];
    const float* bias = (const float*)d_in[2];
    float* out        = (float*)d_out;

    if (ws_size >= WS_NEED_NEW) {
        short* Xp = (short*)d_ws;
        short* Wt = Xp + XP_SHORTS;
        hipMemsetAsync(Xp, 0, XP_SHORTS * sizeof(short), stream);   // zero halo
        prep_x<<<NN * HH, 256, 0, stream>>>(X, Xp);
        prep_w2<<<144, 256, 0, stream>>>(Wsrc, Wt);
        conv_mfma2<<<784, 256, 0, stream>>>(Xp, Wt, bias, out);
    } else if (ws_size >= (size_t)(2 * WT_ELEMS * sizeof(short))) {
        short* whi = (short*)d_ws;
        short* wlo = whi + WT_ELEMS;
        prep_w<<<WT_ELEMS / 256, 256, 0, stream>>>(Wsrc, whi, wlo);
        conv_mfma<<<dim3(784, 2), 256, 0, stream>>>(X, whi, wlo, bias, out);
    } else {
        conv_naive<<<100352, 256, 0, stream>>>(X, Wsrc, bias, out);
    }
}

// Round 5
// 214.971 us; speedup vs baseline: 1.9490x; 1.0641x over previous
//
#include <hip/hip_runtime.h>
#include <hip/hip_bf16.h>

// Conv2d 3x3 s1 p1, NCHW fp32 -> implicit GEMM, f16 MFMA (absmax 0.0625 verified R4).
// Round-5 changes vs R4 (each separately attributable per-dispatch):
//  1. prep_x: coalesced-read LDS-transpose (was ~25%-efficiency strided reads).
//  2. conv: 128x128 tile, double-buffered LDS (64KB), 2-phase prefetch pipeline
//     (global_load_lds of tile k+1 issued before MFMA of tile k; 1 barrier/kstep).

typedef __attribute__((ext_vector_type(8))) _Float16 half8;
typedef __attribute__((ext_vector_type(4))) float floatx4;

#define NN    32
#define CC    128
#define HH    56
#define WW    56
#define KOUT  256
#define HWs   3136                    // 56*56
#define HP    58                      // padded H/W
#define HPP   (HP * HP)               // 3364
#define XP_SHORTS ((size_t)NN * HPP * CC)    // 13,778,944 f16
#define WT_SHORTS (36 * 8192)                // 36 tiles (kstep x kblk), swizzle baked
#define WS_NEED ((XP_SHORTS + WT_SHORTS) * sizeof(short))

__device__ __forceinline__ void gload_lds16(const void* g, void* l) {
    __builtin_amdgcn_global_load_lds(
        (const __attribute__((address_space(1))) unsigned int*)g,
        (__attribute__((address_space(3))) unsigned int*)l, 16, 0, 0);
}

// ---- prep: X[n][c][h][w] fp32 -> Xp[n][h+1][w+1][c] f16, via LDS transpose -
// Reads: consecutive lanes -> consecutive w (coalesced). Writes: consecutive
// lanes -> consecutive c-octets (coalesced 256B runs). LDS row pad 57 words.
__global__ __launch_bounds__(256) void prep_x(const float* __restrict__ X,
                                              short* __restrict__ Xp) {
    __shared__ float xl[128 * 57];
    const int n = blockIdx.x / HH;
    const int h = blockIdx.x % HH;
    const float* src = X + (size_t)n * CC * HWs + h * WW;
    const int tid = threadIdx.x;
#pragma unroll
    for (int it = 0; it < 28; ++it) {          // 28*256 = 7168 = 128c * 56w
        const int idx = it * 256 + tid;
        const int c = idx / 56;
        const int w = idx - c * 56;
        xl[c * 57 + w] = src[(size_t)c * HWs + w];
    }
    __syncthreads();
#pragma unroll
    for (int it = 0; it < 4; ++it) {           // 896 = 56w * 16 octets
        const int u = it * 256 + tid;
        if (u < 896) {
            const int oct = u & 15, w = u >> 4;
            _Float16 v[8];
#pragma unroll
            for (int j = 0; j < 8; ++j)
                v[j] = (_Float16)xl[(oct * 8 + j) * 57 + w];
            *(half8*)&Xp[((size_t)n * HPP + (h + 1) * HP + (w + 1)) * CC + oct * 8] =
                *(half8*)v;
        }
    }
}

// ---- prep: W[k][c][3][3] fp32 -> 36 tiles [kstep][kblk] 128row x 64c, ------
// octet-swizzle (phys_oct = log_oct ^ (row&7)) baked for linear LDS copy.
__global__ __launch_bounds__(256) void prep_w3(const float* __restrict__ Wsrc,
                                               short* __restrict__ Wt) {
    const int gid = blockIdx.x * 256 + threadIdx.x;   // 0..36863 (16B chunks)
    const int t2  = gid >> 10;                        // tile 0..35
    const int u8  = gid & 1023;                       // chunk in tile
    const int r   = u8 >> 3;                          // row 0..127
    const int o   = u8 & 7;                           // phys octet
    const int rs  = t2 >> 2;                          // tap 0..8
    const int ct  = (t2 >> 1) & 1;                    // c-half
    const int kb  = t2 & 1;                           // kblk
    const int k   = kb * 128 + r;
    const int c0  = ct * 64 + ((o ^ (r & 7)) << 3);
    _Float16 v[8];
#pragma unroll
    for (int j = 0; j < 8; ++j)
        v[j] = (_Float16)Wsrc[((size_t)k * CC + c0 + j) * 9 + rs];
    *(half8*)&Wt[(size_t)t2 * 8192 + u8 * 8] = *(half8*)v;
}

// ---- main: 128ch x 128pix tile, 4 waves (wave 64x64), BK=64, dbuf 2-phase --
__global__ __launch_bounds__(256, 2) void conv_mfma3(
    const short* __restrict__ Xp, const short* __restrict__ Wt,
    const float* __restrict__ bias, float* __restrict__ out) {

    __shared__ __align__(16) short smem[32768];   // 64KB = 2 x (A 16KB | B 16KB)

    const int tid  = threadIdx.x;
    const int lane = tid & 63;
    const int wid  = tid >> 6;
    const int wr   = wid >> 1;               // ch 64-half within 128
    const int wc   = wid & 1;                // pix 64-half
    const int bid  = blockIdx.x;             // 0..783
    const int kblk = blockIdx.y;             // 0..1
    const int pblk = (bid & 7) * 98 + (bid >> 3);   // XCD-bijective (784=8*98)

    // B-stage per-lane global bases: 4 chunks, row = wid*32 + i*8 + (lane>>3)
    const int swzoct = (lane & 7) ^ (lane >> 3);    // logical octet (row&7 = lane>>3)
    const short* vsrc[4];
#pragma unroll
    for (int i = 0; i < 4; ++i) {
        const int row = wid * 32 + i * 8 + (lane >> 3);
        const int p   = pblk * 128 + row;
        const int n   = p / HWs;
        const int hw  = p % HWs;
        const int h   = hw / WW;
        const int w   = hw % WW;
        vsrc[i] = Xp + ((size_t)n * HPP + (h + 1) * HP + (w + 1)) * CC + swzoct * 8;
    }

#define STAGE(kk, bb) do {                                                     \
    const int rs_ = (kk) >> 1, ct_ = (kk) & 1;                                 \
    const int tap_ = ((rs_ / 3 - 1) * HP + (rs_ % 3 - 1)) * CC + ct_ * 64;     \
    const short* as_ = Wt + (size_t)((kk) * 2 + kblk) * 8192 + wid * 2048      \
                       + lane * 8;                                             \
    _Pragma("unroll")                                                          \
    for (int i_ = 0; i_ < 4; ++i_)                                             \
        gload_lds16(as_ + i_ * 512, &smem[(bb) + wid * 2048 + i_ * 512]);      \
    _Pragma("unroll")                                                          \
    for (int i_ = 0; i_ < 4; ++i_)                                             \
        gload_lds16(vsrc[i_] + tap_, &smem[(bb) + 8192 + wid * 2048 + i_ * 512]); \
} while (0)

    floatx4 acc[4][4];
#pragma unroll
    for (int i = 0; i < 4; i++)
#pragma unroll
        for (int j = 0; j < 4; j++) acc[i][j] = (floatx4)(0.0f);

    STAGE(0, 0);
    __syncthreads();                          // buf0 ready (drains vmcnt)

    int cur = 0;
    for (int k = 0; k < 18; ++k) {
        const int cb = cur * 16384;
        if (k < 17) STAGE(k + 1, 16384 - cb); // prefetch flies under MFMA

#pragma unroll
        for (int ksub = 0; ksub < 2; ++ksub) {
            const int koct = ksub * 4 + (lane >> 4);
            half8 ah[4], bh[4];
#pragma unroll
            for (int mt = 0; mt < 4; ++mt) {
                const int ar = wr * 64 + mt * 16 + (lane & 15);
                ah[mt] = *(const half8*)&smem[cb + ar * 64 + ((koct ^ (ar & 7)) << 3)];
            }
#pragma unroll
            for (int nt = 0; nt < 4; ++nt) {
                const int br = wc * 64 + nt * 16 + (lane & 15);
                bh[nt] = *(const half8*)&smem[cb + 8192 + br * 64 + ((koct ^ (br & 7)) << 3)];
            }
#pragma unroll
            for (int mt = 0; mt < 4; ++mt)
#pragma unroll
                for (int nt = 0; nt < 4; ++nt)
                    acc[mt][nt] = __builtin_amdgcn_mfma_f32_16x16x32_f16(
                        ah[mt], bh[nt], acc[mt][nt], 0, 0, 0);
        }

        __syncthreads();   // readers done with buf[cur]; prefetch (vmcnt) drained
        cur ^= 1;
    }
#undef STAGE

    // epilogue: C/D col=lane&15 -> pixel, row=(lane>>4)*4+r -> channel
#pragma unroll
    for (int mt = 0; mt < 4; ++mt) {
        const int ch = kblk * 128 + wr * 64 + mt * 16 + ((lane >> 4) << 2);
#pragma unroll
        for (int nt = 0; nt < 4; ++nt) {
            const int p  = pblk * 128 + wc * 64 + nt * 16 + (lane & 15);
            const int n  = p / HWs;          // 16-pix groups never straddle n
            const int hw = p % HWs;
            float* ob = out + ((size_t)n * KOUT + ch) * HWs + hw;
#pragma unroll
            for (int r = 0; r < 4; ++r)
                ob[(size_t)r * HWs] = acc[mt][nt][r] + bias[ch + r];
        }
    }
}

// ---- fallback: correct naive direct conv (only if ws too small) ------------
__global__ __launch_bounds__(256) void conv_naive(const float* __restrict__ X,
                                                  const float* __restrict__ Wt,
                                                  const float* __restrict__ bias,
                                                  float* __restrict__ out) {
    long o = (long)blockIdx.x * 256 + threadIdx.x;
    int w_ = o % WW;
    long t1 = o / WW;
    int h_ = t1 % HH;
    long t2 = t1 / HH;
    int k_ = t2 % KOUT;
    int n_ = (int)(t2 / KOUT);
    float acc = bias[k_];
    for (int c = 0; c < CC; ++c)
        for (int r = 0; r < 3; ++r) {
            int ih = h_ + r - 1;
            if ((unsigned)ih >= 56u) continue;
            for (int s = 0; s < 3; ++s) {
                int iw = w_ + s - 1;
                if ((unsigned)iw >= 56u) continue;
                acc += X[((long)(n_ * CC + c) * HH + ih) * WW + iw] *
                       Wt[((k_ * CC + c) * 3 + r) * 3 + s];
            }
        }
    out[o] = acc;
}

extern "C" void kernel_launch(void* const* d_in, const int* in_sizes, int n_in,
                              void* d_out, int out_size, void* d_ws, size_t ws_size,
                              hipStream_t stream) {
    const float* X    = (const float*)d_in[0];
    const float* Wsrc = (const float*)d_in[1];
    const float* bias = (const float*)d_in[2];
    float* out        = (float*)d_out;

    if (ws_size >= WS_NEED) {
        short* Xp = (short*)d_ws;
        short* Wt = Xp + XP_SHORTS;
        hipMemsetAsync(Xp, 0, XP_SHORTS * sizeof(short), stream);   // zero halo
        prep_x<<<NN * HH, 256, 0, stream>>>(X, Xp);
        prep_w3<<<144, 256, 0, stream>>>(Wsrc, Wt);
        conv_mfma3<<<dim3(784, 2), 256, 0, stream>>>(Xp, Wt, bias, out);
    } else {
        conv_naive<<<100352, 256, 0, stream>>>(X, Wsrc, bias, out);
    }
}

// Round 6
// 213.344 us; speedup vs baseline: 1.9639x; 1.0076x over previous
//
#include <hip/hip_runtime.h>
#include <hip/hip_bf16.h>

// Conv2d 3x3 s1 p1, NCHW fp32 -> implicit GEMM, f16 MFMA (absmax 0.0625 verified R4/R5).
// R6 changes:
//  1. conv: single-buffer 32KB LDS + launch_bounds(256,3) -> 3 blocks/CU (12 waves,
//     m97 geometry). Dbuf removed (R4==R5 proved 1-deep prefetch worthless here).
//  2. prep_x2: float4 loads (7/thread), halo fused (no hipMemsetAsync dispatch).

typedef __attribute__((ext_vector_type(8))) _Float16 half8;
typedef __attribute__((ext_vector_type(4))) float floatx4;

#define NN    32
#define CC    128
#define HH    56
#define WW    56
#define KOUT  256
#define HWs   3136                    // 56*56
#define HP    58                      // padded H/W
#define HPP   (HP * HP)               // 3364
#define XP_SHORTS ((size_t)NN * HPP * CC)    // 13,778,944 f16
#define WT_SHORTS (36 * 8192)                // 36 tiles (tap x c-half x kblk)
#define WS_NEED ((XP_SHORTS + WT_SHORTS) * sizeof(short))

__device__ __forceinline__ void gload_lds16(const void* g, void* l) {
    __builtin_amdgcn_global_load_lds(
        (const __attribute__((address_space(1))) unsigned int*)g,
        (__attribute__((address_space(3))) unsigned int*)l, 16, 0, 0);
}

// ---- prep: X[n][c][h][w] fp32 -> Xp[n][hp][wp][c] f16, halo fused ----------
// Interior rows: float4-coalesced reads -> LDS [128][57] (pad 57: stores <=2-way,
// column reads 4-way = 1.58x) -> coalesced half8 writes. Border rows/cols zeroed
// here (replaces the 27.5MB memset dispatch).
__global__ __launch_bounds__(256) void prep_x2(const float* __restrict__ X,
                                               short* __restrict__ Xp) {
    const int n   = blockIdx.x / HP;        // grid 32*58
    const int hp  = blockIdx.x % HP;
    const int tid = threadIdx.x;
    short* dst = Xp + ((size_t)n * HPP + (size_t)hp * HP) * CC;

    half8 z = {(_Float16)0.f, (_Float16)0.f, (_Float16)0.f, (_Float16)0.f,
               (_Float16)0.f, (_Float16)0.f, (_Float16)0.f, (_Float16)0.f};

    if (hp == 0 || hp == HP - 1) {          // full zero row: 928 half8
#pragma unroll
        for (int it = 0; it < 4; ++it) {
            const int u = it * 256 + tid;
            if (u < 928) *(half8*)&dst[u * 8] = z;
        }
        return;
    }

    const int h = hp - 1;
    __shared__ float xl[128 * 57];
    const float* src = X + (size_t)n * CC * HWs + h * WW;
    // phase 1: 1792 float4 loads (coalesced 224B row-runs), scalar LDS stores
#pragma unroll
    for (int i = 0; i < 7; ++i) {
        const int idx = i * 256 + tid;      // [0,1792)
        const int c   = idx / 14;
        const int w4  = idx - c * 14;
        const floatx4 v = *(const floatx4*)&src[(size_t)c * HWs + w4 * 4];
#pragma unroll
        for (int k = 0; k < 4; ++k) xl[c * 57 + w4 * 4 + k] = v[k];
    }
    __syncthreads();
    // phase 2: transpose out (896 interior + 32 w-halo half8)
#pragma unroll
    for (int it = 0; it < 4; ++it) {
        const int u = it * 256 + tid;
        if (u < 896) {
            const int oct = u & 15, w = u >> 4;
            _Float16 v[8];
#pragma unroll
            for (int j = 0; j < 8; ++j)
                v[j] = (_Float16)xl[(oct * 8 + j) * 57 + w];
            *(half8*)&dst[(w + 1) * CC + oct * 8] = *(half8*)v;
        } else if (u < 928) {
            const int q = u - 896;
            const int oct = q & 15;
            const int wpad = (q >> 4) ? (HP - 1) : 0;
            *(half8*)&dst[wpad * CC + oct * 8] = z;
        }
    }
}

// ---- prep: W[k][c][3][3] fp32 -> 36 tiles [tap][c-half][kblk] 128r x 64c ---
// octet-swizzle (phys_oct = log_oct ^ (row&7)) baked for linear LDS copy.
__global__ __launch_bounds__(256) void prep_w3(const float* __restrict__ Wsrc,
                                               short* __restrict__ Wt) {
    const int gid = blockIdx.x * 256 + threadIdx.x;   // 0..36863 (16B chunks)
    const int t2  = gid >> 10;                        // tile 0..35
    const int u8  = gid & 1023;                       // chunk in tile
    const int r   = u8 >> 3;                          // row 0..127
    const int o   = u8 & 7;                           // phys octet
    const int rs  = t2 >> 2;                          // tap 0..8
    const int ct  = (t2 >> 1) & 1;                    // c-half
    const int kb  = t2 & 1;                           // kblk
    const int k   = kb * 128 + r;
    const int c0  = ct * 64 + ((o ^ (r & 7)) << 3);
    _Float16 v[8];
#pragma unroll
    for (int j = 0; j < 8; ++j)
        v[j] = (_Float16)Wsrc[((size_t)k * CC + c0 + j) * 9 + rs];
    *(half8*)&Wt[(size_t)t2 * 8192 + u8 * 8] = *(half8*)v;
}

// ---- main: 128ch x 128pix tile, 4 waves (wave 64x64), BK=64, single-buffer -
// 32KB LDS + 152 total regs (88 VGPR + 64 AGPR) -> 3 blocks/CU (12 waves).
__global__ __launch_bounds__(256, 3) void conv_mfma4(
    const short* __restrict__ Xp, const short* __restrict__ Wt,
    const float* __restrict__ bias, float* __restrict__ out) {

    __shared__ __align__(16) short smem[16384];   // 32KB: A 0..8191 | B 8192..

    const int tid  = threadIdx.x;
    const int lane = tid & 63;
    const int wid  = tid >> 6;
    const int wr   = wid >> 1;               // ch 64-half within 128
    const int wc   = wid & 1;                // pix 64-half
    const int bid  = blockIdx.x;             // 0..783
    const int kblk = blockIdx.y;             // 0..1
    const int pblk = (bid & 7) * 98 + (bid >> 3);   // XCD-bijective (784=8*98)

    // B-stage per-lane global bases: 4 chunks, row = wid*32 + i*8 + (lane>>3)
    const int swzoct = (lane & 7) ^ (lane >> 3);    // logical octet (row&7 = lane>>3)
    const short* vsrc[4];
#pragma unroll
    for (int i = 0; i < 4; ++i) {
        const int row = wid * 32 + i * 8 + (lane >> 3);
        const int p   = pblk * 128 + row;
        const int n   = p / HWs;
        const int hw  = p % HWs;
        const int h   = hw / WW;
        const int w   = hw % WW;
        vsrc[i] = Xp + ((size_t)n * HPP + (h + 1) * HP + (w + 1)) * CC + swzoct * 8;
    }

    floatx4 acc[4][4];
#pragma unroll
    for (int i = 0; i < 4; i++)
#pragma unroll
        for (int j = 0; j < 4; j++) acc[i][j] = (floatx4)(0.0f);

    for (int k = 0; k < 18; ++k) {
        const int rs = k >> 1, ct = k & 1;
        const int tap = ((rs / 3 - 1) * HP + (rs % 3 - 1)) * CC + ct * 64;

        if (k) __syncthreads();              // all readers of prev step done

        // stage A: 16KB weights (swizzle baked in Wt, linear copy)
        const short* as_ = Wt + (size_t)(k * 2 + kblk) * 8192 + wid * 2048 + lane * 8;
#pragma unroll
        for (int i = 0; i < 4; ++i)
            gload_lds16(as_ + i * 512, &smem[wid * 2048 + i * 512]);
        // stage B: 16KB X tile, per-lane pre-swizzled source
#pragma unroll
        for (int i = 0; i < 4; ++i)
            gload_lds16(vsrc[i] + tap, &smem[8192 + wid * 2048 + i * 512]);

        __syncthreads();                     // drains vmcnt -> tiles ready

#pragma unroll
        for (int ksub = 0; ksub < 2; ++ksub) {
            const int koct = ksub * 4 + (lane >> 4);
            half8 ah[4], bh[4];
#pragma unroll
            for (int mt = 0; mt < 4; ++mt) {
                const int ar = wr * 64 + mt * 16 + (lane & 15);
                ah[mt] = *(const half8*)&smem[ar * 64 + ((koct ^ (ar & 7)) << 3)];
            }
#pragma unroll
            for (int nt = 0; nt < 4; ++nt) {
                const int br = wc * 64 + nt * 16 + (lane & 15);
                bh[nt] = *(const half8*)&smem[8192 + br * 64 + ((koct ^ (br & 7)) << 3)];
            }
#pragma unroll
            for (int mt = 0; mt < 4; ++mt)
#pragma unroll
                for (int nt = 0; nt < 4; ++nt)
                    acc[mt][nt] = __builtin_amdgcn_mfma_f32_16x16x32_f16(
                        ah[mt], bh[nt], acc[mt][nt], 0, 0, 0);
        }
    }

    // epilogue: C/D col=lane&15 -> pixel, row=(lane>>4)*4+r -> channel
#pragma unroll
    for (int mt = 0; mt < 4; ++mt) {
        const int ch = kblk * 128 + wr * 64 + mt * 16 + ((lane >> 4) << 2);
#pragma unroll
        for (int nt = 0; nt < 4; ++nt) {
            const int p  = pblk * 128 + wc * 64 + nt * 16 + (lane & 15);
            const int n  = p / HWs;          // 16-pix groups never straddle n
            const int hw = p % HWs;
            float* ob = out + ((size_t)n * KOUT + ch) * HWs + hw;
#pragma unroll
            for (int r = 0; r < 4; ++r)
                ob[(size_t)r * HWs] = acc[mt][nt][r] + bias[ch + r];
        }
    }
}

// ---- fallback: correct naive direct conv (only if ws too small) ------------
__global__ __launch_bounds__(256) void conv_naive(const float* __restrict__ X,
                                                  const float* __restrict__ Wt,
                                                  const float* __restrict__ bias,
                                                  float* __restrict__ out) {
    long o = (long)blockIdx.x * 256 + threadIdx.x;
    int w_ = o % WW;
    long t1 = o / WW;
    int h_ = t1 % HH;
    long t2 = t1 / HH;
    int k_ = t2 % KOUT;
    int n_ = (int)(t2 / KOUT);
    float acc = bias[k_];
    for (int c = 0; c < CC; ++c)
        for (int r = 0; r < 3; ++r) {
            int ih = h_ + r - 1;
            if ((unsigned)ih >= 56u) continue;
            for (int s = 0; s < 3; ++s) {
                int iw = w_ + s - 1;
                if ((unsigned)iw >= 56u) continue;
                acc += X[((long)(n_ * CC + c) * HH + ih) * WW + iw] *
                       Wt[((k_ * CC + c) * 3 + r) * 3 + s];
            }
        }
    out[o] = acc;
}

extern "C" void kernel_launch(void* const* d_in, const int* in_sizes, int n_in,
                              void* d_out, int out_size, void* d_ws, size_t ws_size,
                              hipStream_t stream) {
    const float* X    = (const float*)d_in[0];
    const float* Wsrc = (const float*)d_in[1];
    const float* bias = (const float*)d_in[2];
    float* out        = (float*)d_out;

    if (ws_size >= WS_NEED) {
        short* Xp = (short*)d_ws;
        short* Wt = Xp + XP_SHORTS;
        prep_x2<<<NN * HP, 256, 0, stream>>>(X, Xp);          // halo fused, no memset
        prep_w3<<<144, 256, 0, stream>>>(Wsrc, Wt);
        conv_mfma4<<<dim3(784, 2), 256, 0, stream>>>(Xp, Wt, bias, out);
    } else {
        conv_naive<<<100352, 256, 0, stream>>>(X, Wsrc, bias, out);
    }
}